// Round 1
// baseline (236.062 us; speedup 1.0000x reference)
//
#include <hip/hip_runtime.h>

// Problem constants (fixed by the reference).
#define BB 4
#define SS 4096
#define DD 2048
#define KK 4
#define D4 (DD / 4)        // 512 float4 channel-groups
#define CHUNK 16           // s-steps per thread
#define NCH (SS / CHUNK)   // 256 chunks per (b, column)

// y[b,s,d] = bias[d] + sum_{k=0..3} x[b, s-3+k, d] * W[d,k]   (zero-pad s<0)
//
// Thread layout: t = ((b * NCH + chunk) * D4 + d4); lanes fastest over d4 so
// every wave issues contiguous 1 KiB dwordx4 transactions. Sliding 3-register
// window over s => exactly 1 load + 1 store per output float4 (+3 halo/chunk).
__global__ __launch_bounds__(256) void shortconv_kernel(
    const float4* __restrict__ x,      // (B,S,D) as float4 over D
    const float4* __restrict__ w4,     // (D,4): w4[d] = {W[d,0],W[d,1],W[d,2],W[d,3]}
    const float4* __restrict__ bias4,  // (D/4)
    float4* __restrict__ y)            // (B,S,D) as float4 over D
{
    const int t    = blockIdx.x * 256 + threadIdx.x;
    const int d4   = t & (D4 - 1);
    const int rest = t >> 9;            // / D4
    const int ch   = rest & (NCH - 1);
    const int b    = rest >> 8;         // / NCH

    // Per-d weight rows: output lane j (d = 4*d4+j) uses row w4[4*d4+j].
    const float4 wr0 = w4[4 * d4 + 0];
    const float4 wr1 = w4[4 * d4 + 1];
    const float4 wr2 = w4[4 * d4 + 2];
    const float4 wr3 = w4[4 * d4 + 3];
    const float4 bv  = bias4[d4];

    const int s0 = ch * CHUNK;
    const size_t base = ((size_t)b * SS + (size_t)s0) * D4 + (size_t)d4;

    float4 x0, x1, x2;  // sliding window: x[s-3], x[s-2], x[s-1]
    if (ch == 0) {
        x0 = make_float4(0.f, 0.f, 0.f, 0.f);
        x1 = x0;
        x2 = x0;
    } else {
        x0 = x[base - 3 * (size_t)D4];
        x1 = x[base - 2 * (size_t)D4];
        x2 = x[base - 1 * (size_t)D4];
    }

#pragma unroll
    for (int i = 0; i < CHUNK; ++i) {
        const float4 x3 = x[base + (size_t)i * D4];
        float4 r;
        r.x = bv.x + wr0.x * x0.x + wr0.y * x1.x + wr0.z * x2.x + wr0.w * x3.x;
        r.y = bv.y + wr1.x * x0.y + wr1.y * x1.y + wr1.z * x2.y + wr1.w * x3.y;
        r.z = bv.z + wr2.x * x0.z + wr2.y * x1.z + wr2.z * x2.z + wr2.w * x3.z;
        r.w = bv.w + wr3.x * x0.w + wr3.y * x1.w + wr3.z * x2.w + wr3.w * x3.w;
        y[base + (size_t)i * D4] = r;
        x0 = x1;
        x1 = x2;
        x2 = x3;
    }
}

extern "C" void kernel_launch(void* const* d_in, const int* in_sizes, int n_in,
                              void* d_out, int out_size, void* d_ws, size_t ws_size,
                              hipStream_t stream) {
    const float* x    = (const float*)d_in[0];  // (B,S,D) fp32
    const float* w    = (const float*)d_in[1];  // (D,1,K) fp32
    const float* bias = (const float*)d_in[2];  // (D,)   fp32
    float* out        = (float*)d_out;          // (B,S,D) fp32

    const int total_threads = BB * NCH * D4;    // 524288 = 8192 waves (fills 256 CUs)
    const int block = 256;
    const int grid  = total_threads / block;    // 2048

    shortconv_kernel<<<grid, block, 0, stream>>>(
        (const float4*)x, (const float4*)w, (const float4*)bias, (float4*)out);
}